// Round 2
// baseline (1498.115 us; speedup 1.0000x reference)
//
#include <hip/hip_runtime.h>
#include <cstdint>
#include <cstddef>

#define DIM   512
#define HEADS 8
#define HD    64
#define FF    2048
#define WINSZ 128
#define BB    8
#define NN    8192
#define NW    (NN / WINSZ)     // 64
#define MROWS (BB * NN)        // 65536
#define QS    ((size_t)BB * HEADS * NN * HD)  // elems per q/k/v tensor

typedef __attribute__((ext_vector_type(8))) _Float16 half8;
typedef __attribute__((ext_vector_type(4))) float floatx4;

__device__ __forceinline__ floatx4 mfma16(half8 a, half8 b, floatx4 c) {
    return __builtin_amdgcn_mfma_f32_16x16x32_f16(a, b, c, 0, 0, 0);
}

__device__ __forceinline__ void gload_lds16(const void* g, void* l) {
    __builtin_amdgcn_global_load_lds(
        (const __attribute__((address_space(1))) void*)g,
        (__attribute__((address_space(3))) void*)l, 16, 0, 0);
}

__device__ __forceinline__ float qmax16(float v) {
    v = fmaxf(v, __shfl_xor(v, 1));
    v = fmaxf(v, __shfl_xor(v, 2));
    v = fmaxf(v, __shfl_xor(v, 4));
    v = fmaxf(v, __shfl_xor(v, 8));
    return v;
}
__device__ __forceinline__ float qsum16(float v) {
    v += __shfl_xor(v, 1);
    v += __shfl_xor(v, 2);
    v += __shfl_xor(v, 4);
    v += __shfl_xor(v, 8);
    return v;
}

// tanh-form GELU, max abs err ~3e-4 vs exact; ~8 VALU ops via v_exp_f32
__device__ __forceinline__ float gelu_f(float x) {
    const float y = 1.5957691216f * (x + 0.044715f * x * x * x);  // 2*sqrt(2/pi)*(...)
    const float t = 1.0f - 2.0f / (__expf(y) + 1.0f);             // tanh(y/2*2)
    return 0.5f * x * (1.0f + t);
}

// ---------------------------------------------------------------------------
// ss[b][j] = silu(t_emb[b]) @ time_w[:, j] + time_b[j]   (j < 1024)
__global__ __launch_bounds__(128)
void time_ss_kernel(const float* __restrict__ t_emb, const float* __restrict__ tw,
                    const float* __restrict__ tb, float* __restrict__ ss) {
    __shared__ float st[512];
    const int b = blockIdx.x;
    for (int i = threadIdx.x; i < 512; i += 128) {
        float v = t_emb[b * 512 + i];
        st[i] = v / (1.0f + expf(-v));
    }
    __syncthreads();
    const int j = blockIdx.y * 128 + threadIdx.x;
    float acc = tb[j];
    for (int i = 0; i < 512; ++i) acc += st[i] * tw[i * 1024 + j];
    ss[b * 1024 + j] = acc;
}

// ---------------------------------------------------------------------------
// weight cast+transpose via LDS tile: w f32 [K][N] -> wt f16 [N][K]
__global__ __launch_bounds__(256)
void wcast_kernel(const float* __restrict__ w, _Float16* __restrict__ wt, int K, int N) {
    __shared__ float t[32][33];
    const int kb = blockIdx.x * 32, nb = blockIdx.y * 32;
    const int tx = threadIdx.x & 31, ty = threadIdx.x >> 5;
#pragma unroll
    for (int i = 0; i < 32; i += 8)
        t[ty + i][tx] = w[(size_t)(kb + ty + i) * N + nb + tx];
    __syncthreads();
#pragma unroll
    for (int i = 0; i < 32; i += 8)
        wt[(size_t)(nb + ty + i) * K + kb + tx] = (_Float16)t[tx][ty + i];
}

// ---------------------------------------------------------------------------
// LayerNorm (+ optional FiLM modulation), one wave per 512-wide row, f16 out
template <bool MOD>
__global__ __launch_bounds__(256)
void ln_kernel(const float* __restrict__ x, const float* __restrict__ g,
               const float* __restrict__ bv, const float* __restrict__ ss,
               _Float16* __restrict__ out) {
    const int row  = blockIdx.x * 4 + (threadIdx.x >> 6);
    const int lane = threadIdx.x & 63;
    const float* xr = x + (size_t)row * DIM;
    const float4 v0 = *(const float4*)(xr + lane * 4);
    const float4 v1 = *(const float4*)(xr + 256 + lane * 4);
    float s  = v0.x + v0.y + v0.z + v0.w + v1.x + v1.y + v1.z + v1.w;
    float s2 = v0.x * v0.x + v0.y * v0.y + v0.z * v0.z + v0.w * v0.w +
               v1.x * v1.x + v1.y * v1.y + v1.z * v1.z + v1.w * v1.w;
#pragma unroll
    for (int m = 1; m < 64; m <<= 1) {
        s  += __shfl_xor(s, m);
        s2 += __shfl_xor(s2, m);
    }
    const float mean = s * (1.0f / 512.0f);
    const float var  = s2 * (1.0f / 512.0f) - mean * mean;
    const float rstd = rsqrtf(var + 1e-5f);
    const int b = row >> 13;
    const float vv[8] = {v0.x, v0.y, v0.z, v0.w, v1.x, v1.y, v1.z, v1.w};
    union { _Float16 h[4]; unsigned long long u; } pk;
#pragma unroll
    for (int half = 0; half < 2; ++half) {
        const int c0 = half * 256 + lane * 4;
#pragma unroll
        for (int i = 0; i < 4; ++i) {
            const int c = c0 + i;
            float y = (vv[half * 4 + i] - mean) * rstd * g[c] + bv[c];
            if (MOD) y = y * (1.0f + ss[b * 1024 + c]) + ss[b * 1024 + 512 + c];
            pk.h[i] = (_Float16)y;
        }
        *(unsigned long long*)(out + (size_t)row * DIM + c0) = pk.u;
    }
}

// ---------------------------------------------------------------------------
// GEMM: C[M,N] = A[M,K] @ BT[N,K]^T + bias, fused epilogue (LDS-vectorized).
// EPI 0: scatter to q/k/v f16    EPI 1: + resid -> f32
// EPI 2: gelu -> f16             EPI 3: + resid -> f32 (final out)
template <int EPI>
__global__ __launch_bounds__(256)
void gemm_bt(const _Float16* __restrict__ A, const _Float16* __restrict__ BT,
             const float* __restrict__ bias, int K, int N,
             const float* __restrict__ resid, float* __restrict__ outf,
             _Float16* __restrict__ outh) {
    __shared__ _Float16 lds[8192];           // lA: [0,4096), lB: [4096,8192)
    _Float16* lA = lds;
    _Float16* lB = lds + 4096;
    const int tid  = threadIdx.x;
    const int wv   = tid >> 6;
    const int lane = tid & 63;
    const int ln   = lane & 15;
    const int qd   = lane >> 4;
    const int wm   = (wv >> 1) * 64;
    const int wn   = (wv & 1) * 64;
    const int m0   = blockIdx.y * 128;
    const int n0   = blockIdx.x * 128;

    floatx4 acc[4][4];
#pragma unroll
    for (int i = 0; i < 4; ++i)
#pragma unroll
        for (int j = 0; j < 4; ++j) acc[i][j] = (floatx4){0.f, 0.f, 0.f, 0.f};

    for (int kt = 0; kt < K; kt += 32) {
        __syncthreads();
#pragma unroll
        for (int i = 0; i < 2; ++i) {
            const int c    = tid + i * 256;          // chunk of 8 f16 (16B)
            const int row  = c >> 2;
            const int kc   = (c & 3) * 8;
            const int base = (wv * 64 + i * 256) * 8;  // wave-uniform LDS base
            gload_lds16(A + (size_t)(m0 + row) * K + kt + kc, &lA[base]);
            gload_lds16(BT + (size_t)(n0 + row) * K + kt + kc, &lB[base]);
        }
        __syncthreads();
        half8 af[4], bf[4];
#pragma unroll
        for (int mi = 0; mi < 4; ++mi)
            af[mi] = *(const half8*)&lA[(wm + mi * 16 + ln) * 32 + qd * 8];
#pragma unroll
        for (int ni = 0; ni < 4; ++ni)
            bf[ni] = *(const half8*)&lB[(wn + ni * 16 + ln) * 32 + qd * 8];
#pragma unroll
        for (int mi = 0; mi < 4; ++mi)
#pragma unroll
            for (int ni = 0; ni < 4; ++ni)
                acc[mi][ni] = mfma16(af[mi], bf[ni], acc[mi][ni]);
    }

    // ---- epilogue via LDS round-trip, 4 quarters of 32 rows ----
    if (EPI == 0 || EPI == 2) {
        _Float16* ot = lds;                          // 32 x 136 f16 (8.7 KB)
#pragma unroll
        for (int q = 0; q < 4; ++q) {
            __syncthreads();
            const int mi0 = (q * 32 - wm) >> 4;      // wave owns this quarter?
            if (mi0 == 0 || mi0 == 2) {
#pragma unroll
                for (int mm = 0; mm < 2; ++mm) {
                    const int mi = mi0 + mm;
#pragma unroll
                    for (int ni = 0; ni < 4; ++ni) {
                        const int col = wn + ni * 16 + ln;
                        const float bb = bias[n0 + col];
#pragma unroll
                        for (int r = 0; r < 4; ++r) {
                            float v = acc[mi][ni][r] + bb;
                            if (EPI == 2) v = gelu_f(v);
                            ot[(mm * 16 + qd * 4 + r) * 136 + col] = (_Float16)v;
                        }
                    }
                }
            }
            __syncthreads();
#pragma unroll
            for (int p = 0; p < 2; ++p) {
                const int lrow = (tid >> 4) + p * 16;
                const int c8   = (tid & 15) * 8;
                half8 hv = *(const half8*)&ot[lrow * 136 + c8];
                const int grow = m0 + q * 32 + lrow;
                const int gc   = n0 + c8;
                if (EPI == 2) {
                    *(half8*)&outh[(size_t)grow * N + gc] = hv;
                } else {  // EPI 0: q/k/v scatter, vectorized along d
                    const int which = gc >> 9;
                    const int h = (gc >> 6) & 7;
                    const int d = gc & 63;
                    const int b = grow >> 13;
                    const int t = grow & 8191;
                    *(half8*)&outh[(size_t)which * QS +
                                   (((size_t)(b * 8 + h) * 8192 + t) << 6) + d] = hv;
                }
            }
        }
    } else {  // EPI 1 / 3 : f32 + residual
        float* otf = (float*)lds;                    // 32 x 128 f32 (16 KB)
#pragma unroll
        for (int q = 0; q < 4; ++q) {
            __syncthreads();
            const int mi0 = (q * 32 - wm) >> 4;
            if (mi0 == 0 || mi0 == 2) {
#pragma unroll
                for (int mm = 0; mm < 2; ++mm) {
                    const int mi = mi0 + mm;
#pragma unroll
                    for (int ni = 0; ni < 4; ++ni) {
                        const int col = wn + ni * 16 + ln;
                        const float bb = bias[n0 + col];
#pragma unroll
                        for (int r = 0; r < 4; ++r)
                            otf[(mm * 16 + qd * 4 + r) * 128 + col] =
                                acc[mi][ni][r] + bb;
                    }
                }
            }
            __syncthreads();
#pragma unroll
            for (int p = 0; p < 4; ++p) {
                const int lrow = (tid >> 5) + p * 8;
                const int c4   = (tid & 31) * 4;
                float4 v = *(const float4*)&otf[lrow * 128 + c4];
                const size_t idx = (size_t)(m0 + q * 32 + lrow) * N + n0 + c4;
                const float4 rr = *(const float4*)&resid[idx];
                v.x += rr.x; v.y += rr.y; v.z += rr.z; v.w += rr.w;
                *(float4*)&outf[idx] = v;
            }
        }
    }
}

// ---------------------------------------------------------------------------
// Windowed attention, one block per (window w, b*H+h). 4 waves x 32 q-rows.
__global__ __launch_bounds__(256)
void attn_kernel(const _Float16* __restrict__ qkv, _Float16* __restrict__ attn) {
    const int w  = blockIdx.x;
    const int bh = blockIdx.y;
    const int tid  = threadIdx.x;
    const int wv   = tid >> 6;
    const int lane = tid & 63;
    const int ln   = lane & 15;
    const int qd   = lane >> 4;

    __shared__ _Float16 vt[64 * 136];        // V^T [d][s], padded
    __shared__ _Float16 pl[4 * 32 * 136];    // per-wave P scratch

    const _Float16* qbuf = qkv;
    const _Float16* kbuf = qkv + QS;
    const _Float16* vbuf = qkv + 2 * QS;
    const size_t bhbase = (size_t)bh * NN * HD;

    half8 qf[2][2];
    const _Float16* qsrc = qbuf + bhbase + (size_t)(w * WINSZ + wv * 32) * HD;
#pragma unroll
    for (int mt = 0; mt < 2; ++mt)
#pragma unroll
        for (int ks = 0; ks < 2; ++ks)
            qf[mt][ks] = *(const half8*)(qsrc + (mt * 16 + ln) * HD + ks * 32 + qd * 8);

    float mrun[2][4], lrun[2][4];
    floatx4 oacc[2][4];
#pragma unroll
    for (int mt = 0; mt < 2; ++mt)
#pragma unroll
        for (int r = 0; r < 4; ++r) { mrun[mt][r] = -3.0e38f; lrun[mt][r] = 0.f; }
#pragma unroll
    for (int mt = 0; mt < 2; ++mt)
#pragma unroll
        for (int dt = 0; dt < 4; ++dt) oacc[mt][dt] = (floatx4){0.f, 0.f, 0.f, 0.f};

    for (int c = 0; c < 3; ++c) {
        const int kvw = w + c - 1;
        if (kvw < 0 || kvw >= NW) continue;   // block-uniform: safe with barriers
        __syncthreads();
        const _Float16* vsrc = vbuf + bhbase + (size_t)kvw * WINSZ * HD;
#pragma unroll
        for (int j = 0; j < 4; ++j) {
            const int cc = tid + j * 256;
            const int s = cc >> 3, d0 = (cc & 7) * 8;
            half8 vvv = *(const half8*)(vsrc + cc * 8);
#pragma unroll
            for (int e = 0; e < 8; ++e) vt[(d0 + e) * 136 + s] = vvv[e];
        }
        __syncthreads();

        const _Float16* ksrc = kbuf + bhbase + (size_t)kvw * WINSZ * HD;
        floatx4 sacc[2][8];
#pragma unroll
        for (int nt = 0; nt < 8; ++nt) {
            half8 b0 = *(const half8*)(ksrc + (nt * 16 + ln) * HD + qd * 8);
            half8 b1 = *(const half8*)(ksrc + (nt * 16 + ln) * HD + 32 + qd * 8);
#pragma unroll
            for (int mt = 0; mt < 2; ++mt) {
                floatx4 t = mfma16(qf[mt][0], b0, (floatx4){0.f, 0.f, 0.f, 0.f});
                sacc[mt][nt] = mfma16(qf[mt][1], b1, t);
            }
        }

        _Float16* pw = pl + wv * 32 * 136;
#pragma unroll
        for (int mt = 0; mt < 2; ++mt) {
#pragma unroll
            for (int r = 0; r < 4; ++r) {
                float mx = -3.0e38f;
#pragma unroll
                for (int nt = 0; nt < 8; ++nt)
                    mx = fmaxf(mx, sacc[mt][nt][r] * 0.125f);
                mx = qmax16(mx);
                const float mnew  = fmaxf(mrun[mt][r], mx);
                const float alpha = __expf(mrun[mt][r] - mnew);
                float rs = 0.f;
#pragma unroll
                for (int nt = 0; nt < 8; ++nt) {
                    const float pv = __expf(sacc[mt][nt][r] * 0.125f - mnew);
                    rs += pv;
                    pw[(mt * 16 + qd * 4 + r) * 136 + nt * 16 + ln] = (_Float16)pv;
                }
                rs = qsum16(rs);
                lrun[mt][r] = lrun[mt][r] * alpha + rs;
                mrun[mt][r] = mnew;
#pragma unroll
                for (int dt = 0; dt < 4; ++dt) oacc[mt][dt][r] *= alpha;
            }
        }

#pragma unroll
        for (int kt = 0; kt < 4; ++kt) {
            half8 pf0 = *(const half8*)(pw + ln * 136 + kt * 32 + qd * 8);
            half8 pf1 = *(const half8*)(pw + (16 + ln) * 136 + kt * 32 + qd * 8);
#pragma unroll
            for (int dt = 0; dt < 4; ++dt) {
                half8 vf = *(const half8*)&vt[(dt * 16 + ln) * 136 + kt * 32 + qd * 8];
                oacc[0][dt] = mfma16(pf0, vf, oacc[0][dt]);
                oacc[1][dt] = mfma16(pf1, vf, oacc[1][dt]);
            }
        }
    }

    const int b = bh >> 3, h = bh & 7;
#pragma unroll
    for (int mt = 0; mt < 2; ++mt) {
#pragma unroll
        for (int dt = 0; dt < 4; ++dt) {
#pragma unroll
            for (int r = 0; r < 4; ++r) {
                const int trow = w * WINSZ + wv * 32 + mt * 16 + qd * 4 + r;
                const int col  = h * HD + dt * 16 + ln;
                attn[((size_t)b * NN + trow) * DIM + col] =
                    (_Float16)(oacc[mt][dt][r] / lrun[mt][r]);
            }
        }
    }
}

// ---------------------------------------------------------------------------
extern "C" void kernel_launch(void* const* d_in, const int* in_sizes, int n_in,
                              void* d_out, int out_size, void* d_ws, size_t ws_size,
                              hipStream_t stream) {
    const float* x      = (const float*)d_in[0];
    const float* t_emb  = (const float*)d_in[1];
    const float* ln1_g  = (const float*)d_in[2];
    const float* ln1_b  = (const float*)d_in[3];
    const float* qkv_w  = (const float*)d_in[4];
    const float* qkv_b  = (const float*)d_in[5];
    const float* proj_w = (const float*)d_in[6];
    const float* proj_b = (const float*)d_in[7];
    const float* ln2_g  = (const float*)d_in[8];
    const float* ln2_b  = (const float*)d_in[9];
    const float* mlp_w1 = (const float*)d_in[10];
    const float* mlp_b1 = (const float*)d_in[11];
    const float* mlp_w2 = (const float*)d_in[12];
    const float* mlp_b2 = (const float*)d_in[13];
    const float* time_w = (const float*)d_in[14];
    const float* time_b = (const float*)d_in[15];
    float* out = (float*)d_out;

    char* p = (char*)d_ws;
    auto alloc = [&](size_t bytes) {
        char* r = p;
        p += (bytes + 255) & ~(size_t)255;
        return r;
    };
    float*    ss   = (float*)alloc(8 * 1024 * 4);
    _Float16* wq   = (_Float16*)alloc((size_t)1536 * 512 * 2);
    _Float16* wp   = (_Float16*)alloc((size_t)512 * 512 * 2);
    _Float16* w1t  = (_Float16*)alloc((size_t)2048 * 512 * 2);
    _Float16* w2t  = (_Float16*)alloc((size_t)512 * 2048 * 2);
    _Float16* h2   = (_Float16*)alloc((size_t)MROWS * 512 * 2);
    float*    x1   = (float*)alloc((size_t)MROWS * 512 * 4);
    _Float16* regA = (_Float16*)alloc((size_t)MROWS * 512 * 2);      // xn / attn
    _Float16* regB = (_Float16*)alloc((size_t)3 * MROWS * 512 * 2);  // q,k,v
    _Float16* xn     = regA;
    _Float16* attn   = regA;
    _Float16* qkvb   = regB;
    _Float16* hidden = regA;  // 268 MB = regA(67) + regB(201), both dead by then
    (void)ws_size; (void)in_sizes; (void)n_in; (void)out_size;

    // 1. weight casts/transposes (f32 [K][N] -> f16 [N][K]), LDS-tiled
    wcast_kernel<<<dim3(512 / 32, 1536 / 32), 256, 0, stream>>>(qkv_w, wq, 512, 1536);
    wcast_kernel<<<dim3(512 / 32, 512 / 32), 256, 0, stream>>>(proj_w, wp, 512, 512);
    wcast_kernel<<<dim3(512 / 32, 2048 / 32), 256, 0, stream>>>(mlp_w1, w1t, 512, 2048);
    wcast_kernel<<<dim3(2048 / 32, 512 / 32), 256, 0, stream>>>(mlp_w2, w2t, 2048, 512);
    // 2. time modulation
    time_ss_kernel<<<dim3(8, 8), 128, 0, stream>>>(t_emb, time_w, time_b, ss);
    // 3. LN1 + FiLM -> xn (f16)
    ln_kernel<true><<<dim3(MROWS / 4), 256, 0, stream>>>(x, ln1_g, ln1_b, ss, xn);
    // 4. QKV GEMM with q/k/v scatter
    gemm_bt<0><<<dim3(1536 / 128, MROWS / 128), 256, 0, stream>>>(
        xn, wq, qkv_b, 512, 1536, nullptr, nullptr, qkvb);
    // 5. windowed attention -> attn (f16, [B][N][DIM])
    attn_kernel<<<dim3(NW, BB * HEADS), 256, 0, stream>>>(qkvb, attn);
    // 6. proj GEMM + residual -> x1 (f32)
    gemm_bt<1><<<dim3(512 / 128, MROWS / 128), 256, 0, stream>>>(
        attn, wp, proj_b, 512, 512, x, x1, nullptr);
    // 7. LN2 -> h2 (f16)
    ln_kernel<false><<<dim3(MROWS / 4), 256, 0, stream>>>(x1, ln2_g, ln2_b, nullptr, h2);
    // 8. MLP1 + fast GELU -> hidden (f16)
    gemm_bt<2><<<dim3(2048 / 128, MROWS / 128), 256, 0, stream>>>(
        h2, w1t, mlp_b1, 512, 2048, nullptr, nullptr, hidden);
    // 9. MLP2 + residual -> out (f32)
    gemm_bt<3><<<dim3(512 / 128, MROWS / 128), 256, 0, stream>>>(
        hidden, w2t, mlp_b2, 2048, 512, x1, out, nullptr);
}

// Round 3
// 1347.493 us; speedup vs baseline: 1.1118x; 1.1118x over previous
//
#include <hip/hip_runtime.h>
#include <cstdint>
#include <cstddef>

#define DIM   512
#define HEADS 8
#define HD    64
#define FF    2048
#define WINSZ 128
#define BB    8
#define NN    8192
#define NW    (NN / WINSZ)     // 64
#define MROWS (BB * NN)        // 65536
#define QS    ((size_t)BB * HEADS * NN * HD)  // elems per q/k/v tensor

typedef __attribute__((ext_vector_type(8))) _Float16 half8;
typedef __attribute__((ext_vector_type(4))) float floatx4;

__device__ __forceinline__ floatx4 mfma16(half8 a, half8 b, floatx4 c) {
    return __builtin_amdgcn_mfma_f32_16x16x32_f16(a, b, c, 0, 0, 0);
}

__device__ __forceinline__ void gload_lds16(const void* g, void* l) {
    __builtin_amdgcn_global_load_lds(
        (const __attribute__((address_space(1))) void*)g,
        (__attribute__((address_space(3))) void*)l, 16, 0, 0);
}

__device__ __forceinline__ float qmax16(float v) {
    v = fmaxf(v, __shfl_xor(v, 1));
    v = fmaxf(v, __shfl_xor(v, 2));
    v = fmaxf(v, __shfl_xor(v, 4));
    v = fmaxf(v, __shfl_xor(v, 8));
    return v;
}
__device__ __forceinline__ float qsum16(float v) {
    v += __shfl_xor(v, 1);
    v += __shfl_xor(v, 2);
    v += __shfl_xor(v, 4);
    v += __shfl_xor(v, 8);
    return v;
}

// tanh-form GELU, max abs err ~3e-4 vs exact; ~10 VALU ops via v_exp_f32
__device__ __forceinline__ float gelu_f(float x) {
    const float y = 1.5957691216f * (x + 0.044715f * x * x * x);  // 2*sqrt(2/pi)*(...)
    const float t = 1.0f - 2.0f / (__expf(y) + 1.0f);             // tanh(y/2)
    return 0.5f * x * (1.0f + t);
}

// ---------------------------------------------------------------------------
// ss[b][j] = silu(t_emb[b]) @ time_w[:, j] + time_b[j]   (j < 1024)
__global__ __launch_bounds__(128)
void time_ss_kernel(const float* __restrict__ t_emb, const float* __restrict__ tw,
                    const float* __restrict__ tb, float* __restrict__ ss) {
    __shared__ float st[512];
    const int b = blockIdx.x;
    for (int i = threadIdx.x; i < 512; i += 128) {
        float v = t_emb[b * 512 + i];
        st[i] = v / (1.0f + expf(-v));
    }
    __syncthreads();
    const int j = blockIdx.y * 128 + threadIdx.x;
    float acc = tb[j];
    for (int i = 0; i < 512; ++i) acc += st[i] * tw[i * 1024 + j];
    ss[b * 1024 + j] = acc;
}

// ---------------------------------------------------------------------------
// weight cast+transpose via LDS tile: w f32 [K][N] -> wt f16 [N][K]
__global__ __launch_bounds__(256)
void wcast_kernel(const float* __restrict__ w, _Float16* __restrict__ wt, int K, int N) {
    __shared__ float t[32][33];
    const int kb = blockIdx.x * 32, nb = blockIdx.y * 32;
    const int tx = threadIdx.x & 31, ty = threadIdx.x >> 5;
#pragma unroll
    for (int i = 0; i < 32; i += 8)
        t[ty + i][tx] = w[(size_t)(kb + ty + i) * N + nb + tx];
    __syncthreads();
#pragma unroll
    for (int i = 0; i < 32; i += 8)
        wt[(size_t)(nb + ty + i) * K + kb + tx] = (_Float16)t[tx][ty + i];
}

// ---------------------------------------------------------------------------
// LayerNorm (+ optional FiLM modulation), one wave per 512-wide row, f16 out
template <bool MOD>
__global__ __launch_bounds__(256)
void ln_kernel(const float* __restrict__ x, const float* __restrict__ g,
               const float* __restrict__ bv, const float* __restrict__ ss,
               _Float16* __restrict__ out) {
    const int row  = blockIdx.x * 4 + (threadIdx.x >> 6);
    const int lane = threadIdx.x & 63;
    const float* xr = x + (size_t)row * DIM;
    const float4 v0 = *(const float4*)(xr + lane * 4);
    const float4 v1 = *(const float4*)(xr + 256 + lane * 4);
    float s  = v0.x + v0.y + v0.z + v0.w + v1.x + v1.y + v1.z + v1.w;
    float s2 = v0.x * v0.x + v0.y * v0.y + v0.z * v0.z + v0.w * v0.w +
               v1.x * v1.x + v1.y * v1.y + v1.z * v1.z + v1.w * v1.w;
#pragma unroll
    for (int m = 1; m < 64; m <<= 1) {
        s  += __shfl_xor(s, m);
        s2 += __shfl_xor(s2, m);
    }
    const float mean = s * (1.0f / 512.0f);
    const float var  = s2 * (1.0f / 512.0f) - mean * mean;
    const float rstd = rsqrtf(var + 1e-5f);
    const int b = row >> 13;
    const float vv[8] = {v0.x, v0.y, v0.z, v0.w, v1.x, v1.y, v1.z, v1.w};
    union { _Float16 h[4]; unsigned long long u; } pk;
#pragma unroll
    for (int half = 0; half < 2; ++half) {
        const int c0 = half * 256 + lane * 4;
#pragma unroll
        for (int i = 0; i < 4; ++i) {
            const int c = c0 + i;
            float y = (vv[half * 4 + i] - mean) * rstd * g[c] + bv[c];
            if (MOD) y = y * (1.0f + ss[b * 1024 + c]) + ss[b * 1024 + 512 + c];
            pk.h[i] = (_Float16)y;
        }
        *(unsigned long long*)(out + (size_t)row * DIM + c0) = pk.u;
    }
}

// ---------------------------------------------------------------------------
// GEMM: C[M,N] = A[M,K] @ BT[N,K]^T + bias, fused epilogue (direct stores).
// EPI 0: scatter to q/k/v f16    EPI 1: + resid -> f32
// EPI 2: gelu -> f16             EPI 3: + resid -> f32 (final out)
template <int EPI>
__global__ __launch_bounds__(256)
void gemm_bt(const _Float16* __restrict__ A, const _Float16* __restrict__ BT,
             const float* __restrict__ bias, int K, int N,
             const float* __restrict__ resid, float* __restrict__ outf,
             _Float16* __restrict__ outh) {
    __shared__ _Float16 lA[128 * 32];
    __shared__ _Float16 lB[128 * 32];
    const int tid  = threadIdx.x;
    const int wv   = tid >> 6;
    const int lane = tid & 63;
    const int ln   = lane & 15;
    const int qd   = lane >> 4;
    const int wm   = (wv >> 1) * 64;
    const int wn   = (wv & 1) * 64;
    const int m0   = blockIdx.y * 128;
    const int n0   = blockIdx.x * 128;

    floatx4 acc[4][4];
#pragma unroll
    for (int i = 0; i < 4; ++i)
#pragma unroll
        for (int j = 0; j < 4; ++j) acc[i][j] = (floatx4){0.f, 0.f, 0.f, 0.f};

    for (int kt = 0; kt < K; kt += 32) {
        __syncthreads();
#pragma unroll
        for (int i = 0; i < 2; ++i) {
            const int c    = tid + i * 256;          // chunk of 8 f16 (16B)
            const int row  = c >> 2;
            const int kc   = (c & 3) * 8;
            const int base = (wv * 64 + i * 256) * 8;  // wave-uniform LDS base
            gload_lds16(A + (size_t)(m0 + row) * K + kt + kc, &lA[base]);
            gload_lds16(BT + (size_t)(n0 + row) * K + kt + kc, &lB[base]);
        }
        __syncthreads();
        half8 af[4], bf[4];
#pragma unroll
        for (int mi = 0; mi < 4; ++mi)
            af[mi] = *(const half8*)&lA[(wm + mi * 16 + ln) * 32 + qd * 8];
#pragma unroll
        for (int ni = 0; ni < 4; ++ni)
            bf[ni] = *(const half8*)&lB[(wn + ni * 16 + ln) * 32 + qd * 8];
#pragma unroll
        for (int mi = 0; mi < 4; ++mi)
#pragma unroll
            for (int ni = 0; ni < 4; ++ni)
                acc[mi][ni] = mfma16(af[mi], bf[ni], acc[mi][ni]);
    }

#pragma unroll
    for (int mi = 0; mi < 4; ++mi) {
#pragma unroll
        for (int ni = 0; ni < 4; ++ni) {
            const int col  = n0 + wn + ni * 16 + ln;
            const float bb = bias[col];
#pragma unroll
            for (int r = 0; r < 4; ++r) {
                const int row = m0 + wm + mi * 16 + qd * 4 + r;
                const float v = acc[mi][ni][r] + bb;
                if (EPI == 0) {
                    const int which = col >> 9, cc = col & 511;
                    const int b = row >> 13, t = row & 8191;
                    const int h = cc >> 6, d = cc & 63;
                    outh[(size_t)which * QS +
                         ((size_t)(b * HEADS + h) * NN + t) * HD + d] = (_Float16)v;
                } else if (EPI == 1 || EPI == 3) {
                    const size_t idx = (size_t)row * N + col;
                    outf[idx] = resid[idx] + v;
                } else {  // EPI == 2 : fast GELU
                    outh[(size_t)row * N + col] = (_Float16)gelu_f(v);
                }
            }
        }
    }
}

// ---------------------------------------------------------------------------
// Windowed attention, one block per (window w, b*H+h). 4 waves x 32 q-rows.
__global__ __launch_bounds__(256)
void attn_kernel(const _Float16* __restrict__ qkv, _Float16* __restrict__ attn) {
    const int w  = blockIdx.x;
    const int bh = blockIdx.y;
    const int tid  = threadIdx.x;
    const int wv   = tid >> 6;
    const int lane = tid & 63;
    const int ln   = lane & 15;
    const int qd   = lane >> 4;

    __shared__ _Float16 vt[64 * 136];        // V^T [d][s], padded
    __shared__ _Float16 pl[4 * 32 * 136];    // per-wave P scratch

    const _Float16* qbuf = qkv;
    const _Float16* kbuf = qkv + QS;
    const _Float16* vbuf = qkv + 2 * QS;
    const size_t bhbase = (size_t)bh * NN * HD;

    half8 qf[2][2];
    const _Float16* qsrc = qbuf + bhbase + (size_t)(w * WINSZ + wv * 32) * HD;
#pragma unroll
    for (int mt = 0; mt < 2; ++mt)
#pragma unroll
        for (int ks = 0; ks < 2; ++ks)
            qf[mt][ks] = *(const half8*)(qsrc + (mt * 16 + ln) * HD + ks * 32 + qd * 8);

    float mrun[2][4], lrun[2][4];
    floatx4 oacc[2][4];
#pragma unroll
    for (int mt = 0; mt < 2; ++mt)
#pragma unroll
        for (int r = 0; r < 4; ++r) { mrun[mt][r] = -3.0e38f; lrun[mt][r] = 0.f; }
#pragma unroll
    for (int mt = 0; mt < 2; ++mt)
#pragma unroll
        for (int dt = 0; dt < 4; ++dt) oacc[mt][dt] = (floatx4){0.f, 0.f, 0.f, 0.f};

    for (int c = 0; c < 3; ++c) {
        const int kvw = w + c - 1;
        if (kvw < 0 || kvw >= NW) continue;   // block-uniform: safe with barriers
        __syncthreads();
        const _Float16* vsrc = vbuf + bhbase + (size_t)kvw * WINSZ * HD;
#pragma unroll
        for (int j = 0; j < 4; ++j) {
            const int cc = tid + j * 256;
            const int s = cc >> 3, d0 = (cc & 7) * 8;
            half8 vvv = *(const half8*)(vsrc + cc * 8);
#pragma unroll
            for (int e = 0; e < 8; ++e) vt[(d0 + e) * 136 + s] = vvv[e];
        }
        __syncthreads();

        const _Float16* ksrc = kbuf + bhbase + (size_t)kvw * WINSZ * HD;
        floatx4 sacc[2][8];
#pragma unroll
        for (int nt = 0; nt < 8; ++nt) {
            half8 b0 = *(const half8*)(ksrc + (nt * 16 + ln) * HD + qd * 8);
            half8 b1 = *(const half8*)(ksrc + (nt * 16 + ln) * HD + 32 + qd * 8);
#pragma unroll
            for (int mt = 0; mt < 2; ++mt) {
                floatx4 t = mfma16(qf[mt][0], b0, (floatx4){0.f, 0.f, 0.f, 0.f});
                sacc[mt][nt] = mfma16(qf[mt][1], b1, t);
            }
        }

        _Float16* pw = pl + wv * 32 * 136;
#pragma unroll
        for (int mt = 0; mt < 2; ++mt) {
#pragma unroll
            for (int r = 0; r < 4; ++r) {
                float mx = -3.0e38f;
#pragma unroll
                for (int nt = 0; nt < 8; ++nt)
                    mx = fmaxf(mx, sacc[mt][nt][r] * 0.125f);
                mx = qmax16(mx);
                const float mnew  = fmaxf(mrun[mt][r], mx);
                const float alpha = __expf(mrun[mt][r] - mnew);
                float rs = 0.f;
#pragma unroll
                for (int nt = 0; nt < 8; ++nt) {
                    const float pv = __expf(sacc[mt][nt][r] * 0.125f - mnew);
                    rs += pv;
                    pw[(mt * 16 + qd * 4 + r) * 136 + nt * 16 + ln] = (_Float16)pv;
                }
                rs = qsum16(rs);
                lrun[mt][r] = lrun[mt][r] * alpha + rs;
                mrun[mt][r] = mnew;
#pragma unroll
                for (int dt = 0; dt < 4; ++dt) oacc[mt][dt][r] *= alpha;
            }
        }

#pragma unroll
        for (int kt = 0; kt < 4; ++kt) {
            half8 pf0 = *(const half8*)(pw + ln * 136 + kt * 32 + qd * 8);
            half8 pf1 = *(const half8*)(pw + (16 + ln) * 136 + kt * 32 + qd * 8);
#pragma unroll
            for (int dt = 0; dt < 4; ++dt) {
                half8 vf = *(const half8*)&vt[(dt * 16 + ln) * 136 + kt * 32 + qd * 8];
                oacc[0][dt] = mfma16(pf0, vf, oacc[0][dt]);
                oacc[1][dt] = mfma16(pf1, vf, oacc[1][dt]);
            }
        }
    }

    const int b = bh >> 3, h = bh & 7;
#pragma unroll
    for (int mt = 0; mt < 2; ++mt) {
#pragma unroll
        for (int dt = 0; dt < 4; ++dt) {
#pragma unroll
            for (int r = 0; r < 4; ++r) {
                const int trow = w * WINSZ + wv * 32 + mt * 16 + qd * 4 + r;
                const int col  = h * HD + dt * 16 + ln;
                attn[((size_t)b * NN + trow) * DIM + col] =
                    (_Float16)(oacc[mt][dt][r] / lrun[mt][r]);
            }
        }
    }
}

// ---------------------------------------------------------------------------
extern "C" void kernel_launch(void* const* d_in, const int* in_sizes, int n_in,
                              void* d_out, int out_size, void* d_ws, size_t ws_size,
                              hipStream_t stream) {
    const float* x      = (const float*)d_in[0];
    const float* t_emb  = (const float*)d_in[1];
    const float* ln1_g  = (const float*)d_in[2];
    const float* ln1_b  = (const float*)d_in[3];
    const float* qkv_w  = (const float*)d_in[4];
    const float* qkv_b  = (const float*)d_in[5];
    const float* proj_w = (const float*)d_in[6];
    const float* proj_b = (const float*)d_in[7];
    const float* ln2_g  = (const float*)d_in[8];
    const float* ln2_b  = (const float*)d_in[9];
    const float* mlp_w1 = (const float*)d_in[10];
    const float* mlp_b1 = (const float*)d_in[11];
    const float* mlp_w2 = (const float*)d_in[12];
    const float* mlp_b2 = (const float*)d_in[13];
    const float* time_w = (const float*)d_in[14];
    const float* time_b = (const float*)d_in[15];
    float* out = (float*)d_out;

    char* p = (char*)d_ws;
    auto alloc = [&](size_t bytes) {
        char* r = p;
        p += (bytes + 255) & ~(size_t)255;
        return r;
    };
    float*    ss   = (float*)alloc(8 * 1024 * 4);
    _Float16* wq   = (_Float16*)alloc((size_t)1536 * 512 * 2);
    _Float16* wp   = (_Float16*)alloc((size_t)512 * 512 * 2);
    _Float16* w1t  = (_Float16*)alloc((size_t)2048 * 512 * 2);
    _Float16* w2t  = (_Float16*)alloc((size_t)512 * 2048 * 2);
    _Float16* h2   = (_Float16*)alloc((size_t)MROWS * 512 * 2);
    float*    x1   = (float*)alloc((size_t)MROWS * 512 * 4);
    _Float16* regA = (_Float16*)alloc((size_t)MROWS * 512 * 2);      // xn / attn
    _Float16* regB = (_Float16*)alloc((size_t)3 * MROWS * 512 * 2);  // q,k,v
    _Float16* xn     = regA;
    _Float16* attn   = regA;
    _Float16* qkvb   = regB;
    _Float16* hidden = regA;  // 268 MB = regA(67) + regB(201), both dead by then
    (void)ws_size; (void)in_sizes; (void)n_in; (void)out_size;

    // 1. weight casts/transposes (f32 [K][N] -> f16 [N][K]), LDS-tiled
    wcast_kernel<<<dim3(512 / 32, 1536 / 32), 256, 0, stream>>>(qkv_w, wq, 512, 1536);
    wcast_kernel<<<dim3(512 / 32, 512 / 32), 256, 0, stream>>>(proj_w, wp, 512, 512);
    wcast_kernel<<<dim3(512 / 32, 2048 / 32), 256, 0, stream>>>(mlp_w1, w1t, 512, 2048);
    wcast_kernel<<<dim3(2048 / 32, 512 / 32), 256, 0, stream>>>(mlp_w2, w2t, 2048, 512);
    // 2. time modulation
    time_ss_kernel<<<dim3(8, 8), 128, 0, stream>>>(t_emb, time_w, time_b, ss);
    // 3. LN1 + FiLM -> xn (f16)
    ln_kernel<true><<<dim3(MROWS / 4), 256, 0, stream>>>(x, ln1_g, ln1_b, ss, xn);
    // 4. QKV GEMM with q/k/v scatter
    gemm_bt<0><<<dim3(1536 / 128, MROWS / 128), 256, 0, stream>>>(
        xn, wq, qkv_b, 512, 1536, nullptr, nullptr, qkvb);
    // 5. windowed attention -> attn (f16, [B][N][DIM])
    attn_kernel<<<dim3(NW, BB * HEADS), 256, 0, stream>>>(qkvb, attn);
    // 6. proj GEMM + residual -> x1 (f32)
    gemm_bt<1><<<dim3(512 / 128, MROWS / 128), 256, 0, stream>>>(
        attn, wp, proj_b, 512, 512, x, x1, nullptr);
    // 7. LN2 -> h2 (f16)
    ln_kernel<false><<<dim3(MROWS / 4), 256, 0, stream>>>(x1, ln2_g, ln2_b, nullptr, h2);
    // 8. MLP1 + fast GELU -> hidden (f16)
    gemm_bt<2><<<dim3(2048 / 128, MROWS / 128), 256, 0, stream>>>(
        h2, w1t, mlp_b1, 512, 2048, nullptr, nullptr, hidden);
    // 9. MLP2 + residual -> out (f32)
    gemm_bt<3><<<dim3(512 / 128, MROWS / 128), 256, 0, stream>>>(
        hidden, w2t, mlp_b2, 2048, 512, x1, out, nullptr);
}

// Round 4
// 1263.520 us; speedup vs baseline: 1.1857x; 1.0665x over previous
//
#include <hip/hip_runtime.h>
#include <cstdint>
#include <cstddef>

#define DIM   512
#define HEADS 8
#define HD    64
#define FF    2048
#define WINSZ 128
#define BB    8
#define NN    8192
#define NW    (NN / WINSZ)     // 64
#define MROWS (BB * NN)        // 65536
#define QS    ((size_t)BB * HEADS * NN * HD)  // elems per q/k/v tensor

typedef __attribute__((ext_vector_type(8))) _Float16 half8;
typedef __attribute__((ext_vector_type(4))) float floatx4;

__device__ __forceinline__ floatx4 mfma16(half8 a, half8 b, floatx4 c) {
    return __builtin_amdgcn_mfma_f32_16x16x32_f16(a, b, c, 0, 0, 0);
}

__device__ __forceinline__ void gload_lds16(const void* g, void* l) {
    __builtin_amdgcn_global_load_lds(
        (const __attribute__((address_space(1))) void*)g,
        (__attribute__((address_space(3))) void*)l, 16, 0, 0);
}

__device__ __forceinline__ float qmax16(float v) {
    v = fmaxf(v, __shfl_xor(v, 1));
    v = fmaxf(v, __shfl_xor(v, 2));
    v = fmaxf(v, __shfl_xor(v, 4));
    v = fmaxf(v, __shfl_xor(v, 8));
    return v;
}
__device__ __forceinline__ float qsum16(float v) {
    v += __shfl_xor(v, 1);
    v += __shfl_xor(v, 2);
    v += __shfl_xor(v, 4);
    v += __shfl_xor(v, 8);
    return v;
}

// tanh-form GELU, max abs err ~3e-4 vs exact
__device__ __forceinline__ float gelu_f(float x) {
    const float y = 1.5957691216f * (x + 0.044715f * x * x * x);
    const float t = 1.0f - 2.0f / (__expf(y) + 1.0f);
    return 0.5f * x * (1.0f + t);
}

// ---------------------------------------------------------------------------
// ss[b][j] = silu(t_emb[b]) @ time_w[:, j] + time_b[j]   (j < 1024)
__global__ __launch_bounds__(128)
void time_ss_kernel(const float* __restrict__ t_emb, const float* __restrict__ tw,
                    const float* __restrict__ tb, float* __restrict__ ss) {
    __shared__ float st[512];
    const int b = blockIdx.x;
    for (int i = threadIdx.x; i < 512; i += 128) {
        float v = t_emb[b * 512 + i];
        st[i] = v / (1.0f + expf(-v));
    }
    __syncthreads();
    const int j = blockIdx.y * 128 + threadIdx.x;
    float acc = tb[j];
    for (int i = 0; i < 512; ++i) acc += st[i] * tw[i * 1024 + j];
    ss[b * 1024 + j] = acc;
}

// ---------------------------------------------------------------------------
// weight cast+transpose via LDS tile: w f32 [K][N] -> wt f16 [N][K]
__global__ __launch_bounds__(256)
void wcast_kernel(const float* __restrict__ w, _Float16* __restrict__ wt, int K, int N) {
    __shared__ float t[32][33];
    const int kb = blockIdx.x * 32, nb = blockIdx.y * 32;
    const int tx = threadIdx.x & 31, ty = threadIdx.x >> 5;
#pragma unroll
    for (int i = 0; i < 32; i += 8)
        t[ty + i][tx] = w[(size_t)(kb + ty + i) * N + nb + tx];
    __syncthreads();
#pragma unroll
    for (int i = 0; i < 32; i += 8)
        wt[(size_t)(nb + ty + i) * K + kb + tx] = (_Float16)t[tx][ty + i];
}

// ---------------------------------------------------------------------------
// LayerNorm + FiLM, f32 input, one wave per row, f16 out  (LN1)
__global__ __launch_bounds__(256)
void ln_kernel(const float* __restrict__ x, const float* __restrict__ g,
               const float* __restrict__ bv, const float* __restrict__ ss,
               _Float16* __restrict__ out) {
    const int row  = blockIdx.x * 4 + (threadIdx.x >> 6);
    const int lane = threadIdx.x & 63;
    const float* xr = x + (size_t)row * DIM;
    const float4 v0 = *(const float4*)(xr + lane * 4);
    const float4 v1 = *(const float4*)(xr + 256 + lane * 4);
    float s  = v0.x + v0.y + v0.z + v0.w + v1.x + v1.y + v1.z + v1.w;
    float s2 = v0.x * v0.x + v0.y * v0.y + v0.z * v0.z + v0.w * v0.w +
               v1.x * v1.x + v1.y * v1.y + v1.z * v1.z + v1.w * v1.w;
#pragma unroll
    for (int m = 1; m < 64; m <<= 1) {
        s  += __shfl_xor(s, m);
        s2 += __shfl_xor(s2, m);
    }
    const float mean = s * (1.0f / 512.0f);
    const float var  = s2 * (1.0f / 512.0f) - mean * mean;
    const float rstd = rsqrtf(var + 1e-5f);
    const int b = row >> 13;
    const float vv[8] = {v0.x, v0.y, v0.z, v0.w, v1.x, v1.y, v1.z, v1.w};
    union { _Float16 h[4]; unsigned long long u; } pk;
#pragma unroll
    for (int half = 0; half < 2; ++half) {
        const int c0 = half * 256 + lane * 4;
#pragma unroll
        for (int i = 0; i < 4; ++i) {
            const int c = c0 + i;
            float y = (vv[half * 4 + i] - mean) * rstd * g[c] + bv[c];
            y = y * (1.0f + ss[b * 1024 + c]) + ss[b * 1024 + 512 + c];
            pk.h[i] = (_Float16)y;
        }
        *(unsigned long long*)(out + (size_t)row * DIM + c0) = pk.u;
    }
}

// LayerNorm, f16 input, one wave per row, f16 out  (LN2)
__global__ __launch_bounds__(256)
void ln_h_kernel(const _Float16* __restrict__ x, const float* __restrict__ g,
                 const float* __restrict__ bv, _Float16* __restrict__ out) {
    const int row  = blockIdx.x * 4 + (threadIdx.x >> 6);
    const int lane = threadIdx.x & 63;
    half8 v = *(const half8*)(x + (size_t)row * DIM + lane * 8);
    float f[8];
    float s = 0.f, s2 = 0.f;
#pragma unroll
    for (int i = 0; i < 8; ++i) {
        f[i] = (float)v[i];
        s += f[i];
        s2 += f[i] * f[i];
    }
#pragma unroll
    for (int m = 1; m < 64; m <<= 1) {
        s  += __shfl_xor(s, m);
        s2 += __shfl_xor(s2, m);
    }
    const float mean = s * (1.0f / 512.0f);
    const float var  = s2 * (1.0f / 512.0f) - mean * mean;
    const float rstd = rsqrtf(var + 1e-5f);
    half8 o;
#pragma unroll
    for (int i = 0; i < 8; ++i) {
        const int c = lane * 8 + i;
        o[i] = (_Float16)((f[i] - mean) * rstd * g[c] + bv[c]);
    }
    *(half8*)(out + (size_t)row * DIM + lane * 8) = o;
}

// ---------------------------------------------------------------------------
// GEMM: C[M,N] = A[M,K] @ BT[N,K]^T + bias. BK=64, XOR-swizzled LDS,
// XCD-aware block swizzle, direct-store fused epilogues.
// EPI 0: scatter to q/k/v f16    EPI 1: + residf(f32) -> f16
// EPI 2: gelu -> f16             EPI 3: + residh(f16) -> f32 (final out)
template <int EPI>
__global__ __launch_bounds__(256)
void gemm_bt(const _Float16* __restrict__ A, const _Float16* __restrict__ BT,
             const float* __restrict__ bias, int K, int N,
             const float* __restrict__ residf, const _Float16* __restrict__ residh,
             float* __restrict__ outf, _Float16* __restrict__ outh) {
    __shared__ _Float16 lA[128 * 64];
    __shared__ _Float16 lB[128 * 64];
    const int tid  = threadIdx.x;
    const int wv   = tid >> 6;
    const int lane = tid & 63;
    const int ln   = lane & 15;
    const int qd   = lane >> 4;
    const int wm   = (wv >> 1) * 64;
    const int wn   = (wv & 1) * 64;

    // XCD swizzle: all column-tiles of an M-strip share l%8 (same XCD),
    // spaced 8 apart in dispatch order -> A strip stays in that XCD's L2.
    const int nbx = gridDim.x;
    const int l   = blockIdx.y * nbx + blockIdx.x;
    const int grp = l / (nbx * 8);
    const int rem = l - grp * (nbx * 8);
    const int m0  = (grp * 8 + (rem & 7)) * 128;
    const int n0  = (rem >> 3) * 128;

    floatx4 acc[4][4];
#pragma unroll
    for (int i = 0; i < 4; ++i)
#pragma unroll
        for (int j = 0; j < 4; ++j) acc[i][j] = (floatx4){0.f, 0.f, 0.f, 0.f};

    for (int kt = 0; kt < K; kt += 64) {
        __syncthreads();
#pragma unroll
        for (int i = 0; i < 4; ++i) {
            const int c   = tid + i * 256;        // chunk id 0..1023 (8 f16 each)
            const int row = c >> 3;
            const int src = ((c & 7) ^ (row & 7)) * 8;  // XOR bank swizzle
            const int base = (wv * 64 + i * 256) * 8;   // wave-uniform LDS base
            gload_lds16(A + (size_t)(m0 + row) * K + kt + src, &lA[base]);
            gload_lds16(BT + (size_t)(n0 + row) * K + kt + src, &lB[base]);
        }
        __syncthreads();
#pragma unroll
        for (int ks = 0; ks < 2; ++ks) {
            half8 af[4], bf[4];
#pragma unroll
            for (int mi = 0; mi < 4; ++mi) {
                const int row = wm + mi * 16 + ln;
                af[mi] = *(const half8*)&lA[row * 64 + (((ks * 4 + qd) ^ (row & 7)) << 3)];
            }
#pragma unroll
            for (int ni = 0; ni < 4; ++ni) {
                const int row = wn + ni * 16 + ln;
                bf[ni] = *(const half8*)&lB[row * 64 + (((ks * 4 + qd) ^ (row & 7)) << 3)];
            }
#pragma unroll
            for (int mi = 0; mi < 4; ++mi)
#pragma unroll
                for (int ni = 0; ni < 4; ++ni)
                    acc[mi][ni] = mfma16(af[mi], bf[ni], acc[mi][ni]);
        }
    }

#pragma unroll
    for (int mi = 0; mi < 4; ++mi) {
#pragma unroll
        for (int ni = 0; ni < 4; ++ni) {
            const int col  = n0 + wn + ni * 16 + ln;
            const float bb = bias[col];
#pragma unroll
            for (int r = 0; r < 4; ++r) {
                const int row = m0 + wm + mi * 16 + qd * 4 + r;
                const float v = acc[mi][ni][r] + bb;
                if (EPI == 0) {
                    const int which = col >> 9, cc = col & 511;
                    const int b = row >> 13, t = row & 8191;
                    const int h = cc >> 6, d = cc & 63;
                    outh[(size_t)which * QS +
                         ((size_t)(b * HEADS + h) * NN + t) * HD + d] = (_Float16)v;
                } else if (EPI == 1) {
                    const size_t idx = (size_t)row * N + col;
                    outh[idx] = (_Float16)(residf[idx] + v);
                } else if (EPI == 3) {
                    const size_t idx = (size_t)row * N + col;
                    outf[idx] = (float)residh[idx] + v;
                } else {  // EPI == 2 : fast GELU
                    outh[(size_t)row * N + col] = (_Float16)gelu_f(v);
                }
            }
        }
    }
}

// ---------------------------------------------------------------------------
// Windowed attention, one block per (window w, b*H+h). 4 waves x 32 q-rows.
__global__ __launch_bounds__(256)
void attn_kernel(const _Float16* __restrict__ qkv, _Float16* __restrict__ attn) {
    const int w  = blockIdx.x;
    const int bh = blockIdx.y;
    const int tid  = threadIdx.x;
    const int wv   = tid >> 6;
    const int lane = tid & 63;
    const int ln   = lane & 15;
    const int qd   = lane >> 4;

    __shared__ _Float16 vt[64 * 136];        // V^T [d][s], padded
    __shared__ _Float16 pl[4 * 32 * 136];    // per-wave P scratch

    const _Float16* qbuf = qkv;
    const _Float16* kbuf = qkv + QS;
    const _Float16* vbuf = qkv + 2 * QS;
    const size_t bhbase = (size_t)bh * NN * HD;

    half8 qf[2][2];
    const _Float16* qsrc = qbuf + bhbase + (size_t)(w * WINSZ + wv * 32) * HD;
#pragma unroll
    for (int mt = 0; mt < 2; ++mt)
#pragma unroll
        for (int ks = 0; ks < 2; ++ks)
            qf[mt][ks] = *(const half8*)(qsrc + (mt * 16 + ln) * HD + ks * 32 + qd * 8);

    float mrun[2][4], lrun[2][4];
    floatx4 oacc[2][4];
#pragma unroll
    for (int mt = 0; mt < 2; ++mt)
#pragma unroll
        for (int r = 0; r < 4; ++r) { mrun[mt][r] = -3.0e38f; lrun[mt][r] = 0.f; }
#pragma unroll
    for (int mt = 0; mt < 2; ++mt)
#pragma unroll
        for (int dt = 0; dt < 4; ++dt) oacc[mt][dt] = (floatx4){0.f, 0.f, 0.f, 0.f};

    for (int c = 0; c < 3; ++c) {
        const int kvw = w + c - 1;
        if (kvw < 0 || kvw >= NW) continue;   // block-uniform: safe with barriers
        __syncthreads();
        const _Float16* vsrc = vbuf + bhbase + (size_t)kvw * WINSZ * HD;
#pragma unroll
        for (int j = 0; j < 4; ++j) {
            const int cc = tid + j * 256;
            const int s = cc >> 3, d0 = (cc & 7) * 8;
            half8 vvv = *(const half8*)(vsrc + cc * 8);
#pragma unroll
            for (int e = 0; e < 8; ++e) vt[(d0 + e) * 136 + s] = vvv[e];
        }
        __syncthreads();

        const _Float16* ksrc = kbuf + bhbase + (size_t)kvw * WINSZ * HD;
        floatx4 sacc[2][8];
#pragma unroll
        for (int nt = 0; nt < 8; ++nt) {
            half8 b0 = *(const half8*)(ksrc + (nt * 16 + ln) * HD + qd * 8);
            half8 b1 = *(const half8*)(ksrc + (nt * 16 + ln) * HD + 32 + qd * 8);
#pragma unroll
            for (int mt = 0; mt < 2; ++mt) {
                floatx4 t = mfma16(qf[mt][0], b0, (floatx4){0.f, 0.f, 0.f, 0.f});
                sacc[mt][nt] = mfma16(qf[mt][1], b1, t);
            }
        }

        _Float16* pw = pl + wv * 32 * 136;
#pragma unroll
        for (int mt = 0; mt < 2; ++mt) {
#pragma unroll
            for (int r = 0; r < 4; ++r) {
                float mx = -3.0e38f;
#pragma unroll
                for (int nt = 0; nt < 8; ++nt)
                    mx = fmaxf(mx, sacc[mt][nt][r] * 0.125f);
                mx = qmax16(mx);
                const float mnew  = fmaxf(mrun[mt][r], mx);
                const float alpha = __expf(mrun[mt][r] - mnew);
                float rs = 0.f;
#pragma unroll
                for (int nt = 0; nt < 8; ++nt) {
                    const float pv = __expf(sacc[mt][nt][r] * 0.125f - mnew);
                    rs += pv;
                    pw[(mt * 16 + qd * 4 + r) * 136 + nt * 16 + ln] = (_Float16)pv;
                }
                rs = qsum16(rs);
                lrun[mt][r] = lrun[mt][r] * alpha + rs;
                mrun[mt][r] = mnew;
#pragma unroll
                for (int dt = 0; dt < 4; ++dt) oacc[mt][dt][r] *= alpha;
            }
        }

#pragma unroll
        for (int kt = 0; kt < 4; ++kt) {
            half8 pf0 = *(const half8*)(pw + ln * 136 + kt * 32 + qd * 8);
            half8 pf1 = *(const half8*)(pw + (16 + ln) * 136 + kt * 32 + qd * 8);
#pragma unroll
            for (int dt = 0; dt < 4; ++dt) {
                half8 vf = *(const half8*)&vt[(dt * 16 + ln) * 136 + kt * 32 + qd * 8];
                oacc[0][dt] = mfma16(pf0, vf, oacc[0][dt]);
                oacc[1][dt] = mfma16(pf1, vf, oacc[1][dt]);
            }
        }
    }

    const int b = bh >> 3, h = bh & 7;
#pragma unroll
    for (int mt = 0; mt < 2; ++mt) {
#pragma unroll
        for (int dt = 0; dt < 4; ++dt) {
#pragma unroll
            for (int r = 0; r < 4; ++r) {
                const int trow = w * WINSZ + wv * 32 + mt * 16 + qd * 4 + r;
                const int col  = h * HD + dt * 16 + ln;
                attn[((size_t)b * NN + trow) * DIM + col] =
                    (_Float16)(oacc[mt][dt][r] / lrun[mt][r]);
            }
        }
    }
}

// ---------------------------------------------------------------------------
extern "C" void kernel_launch(void* const* d_in, const int* in_sizes, int n_in,
                              void* d_out, int out_size, void* d_ws, size_t ws_size,
                              hipStream_t stream) {
    const float* x      = (const float*)d_in[0];
    const float* t_emb  = (const float*)d_in[1];
    const float* ln1_g  = (const float*)d_in[2];
    const float* ln1_b  = (const float*)d_in[3];
    const float* qkv_w  = (const float*)d_in[4];
    const float* qkv_b  = (const float*)d_in[5];
    const float* proj_w = (const float*)d_in[6];
    const float* proj_b = (const float*)d_in[7];
    const float* ln2_g  = (const float*)d_in[8];
    const float* ln2_b  = (const float*)d_in[9];
    const float* mlp_w1 = (const float*)d_in[10];
    const float* mlp_b1 = (const float*)d_in[11];
    const float* mlp_w2 = (const float*)d_in[12];
    const float* mlp_b2 = (const float*)d_in[13];
    const float* time_w = (const float*)d_in[14];
    const float* time_b = (const float*)d_in[15];
    float* out = (float*)d_out;

    char* p = (char*)d_ws;
    auto alloc = [&](size_t bytes) {
        char* r = p;
        p += (bytes + 255) & ~(size_t)255;
        return r;
    };
    float*    ss   = (float*)alloc(8 * 1024 * 4);
    _Float16* wq   = (_Float16*)alloc((size_t)1536 * 512 * 2);
    _Float16* wp   = (_Float16*)alloc((size_t)512 * 512 * 2);
    _Float16* w1t  = (_Float16*)alloc((size_t)2048 * 512 * 2);
    _Float16* w2t  = (_Float16*)alloc((size_t)512 * 2048 * 2);
    _Float16* h2   = (_Float16*)alloc((size_t)MROWS * 512 * 2);
    _Float16* x1h  = (_Float16*)alloc((size_t)MROWS * 512 * 2);     // f16 now
    _Float16* regA = (_Float16*)alloc((size_t)MROWS * 512 * 2);      // xn / attn
    _Float16* regB = (_Float16*)alloc((size_t)3 * MROWS * 512 * 2);  // q,k,v
    _Float16* xn     = regA;
    _Float16* attn   = regA;
    _Float16* qkvb   = regB;
    _Float16* hidden = regA;  // 268 MB = regA(67) + regB(201), both dead by then
    (void)ws_size; (void)in_sizes; (void)n_in; (void)out_size;

    // 1. weight casts/transposes (f32 [K][N] -> f16 [N][K]), LDS-tiled
    wcast_kernel<<<dim3(512 / 32, 1536 / 32), 256, 0, stream>>>(qkv_w, wq, 512, 1536);
    wcast_kernel<<<dim3(512 / 32, 512 / 32), 256, 0, stream>>>(proj_w, wp, 512, 512);
    wcast_kernel<<<dim3(512 / 32, 2048 / 32), 256, 0, stream>>>(mlp_w1, w1t, 512, 2048);
    wcast_kernel<<<dim3(2048 / 32, 512 / 32), 256, 0, stream>>>(mlp_w2, w2t, 2048, 512);
    // 2. time modulation
    time_ss_kernel<<<dim3(8, 8), 128, 0, stream>>>(t_emb, time_w, time_b, ss);
    // 3. LN1 + FiLM -> xn (f16)
    ln_kernel<<<dim3(MROWS / 4), 256, 0, stream>>>(x, ln1_g, ln1_b, ss, xn);
    // 4. QKV GEMM with q/k/v scatter
    gemm_bt<0><<<dim3(1536 / 128, MROWS / 128), 256, 0, stream>>>(
        xn, wq, qkv_b, 512, 1536, nullptr, nullptr, nullptr, qkvb);
    // 5. windowed attention -> attn (f16, [B][N][DIM])
    attn_kernel<<<dim3(NW, BB * HEADS), 256, 0, stream>>>(qkvb, attn);
    // 6. proj GEMM + residual(x f32) -> x1h (f16)
    gemm_bt<1><<<dim3(512 / 128, MROWS / 128), 256, 0, stream>>>(
        attn, wp, proj_b, 512, 512, x, nullptr, nullptr, x1h);
    // 7. LN2 (f16 in) -> h2 (f16)
    ln_h_kernel<<<dim3(MROWS / 4), 256, 0, stream>>>(x1h, ln2_g, ln2_b, h2);
    // 8. MLP1 + fast GELU -> hidden (f16)
    gemm_bt<2><<<dim3(2048 / 128, MROWS / 128), 256, 0, stream>>>(
        h2, w1t, mlp_b1, 512, 2048, nullptr, nullptr, nullptr, hidden);
    // 9. MLP2 + residual(x1h f16) -> out (f32)
    gemm_bt<3><<<dim3(512 / 128, MROWS / 128), 256, 0, stream>>>(
        hidden, w2t, mlp_b2, 2048, 512, nullptr, x1h, out, nullptr);
}